// Round 1
// baseline (747.574 us; speedup 1.0000x reference)
//
#include <hip/hip_runtime.h>
#include <hip/hip_bf16.h>
#include <cmath>

typedef __bf16 bf16_t;
typedef bf16_t bf16x8 __attribute__((ext_vector_type(8)));
typedef float floatx4 __attribute__((ext_vector_type(4)));

#define NFEAT 26
#define DIM 64
#define DENSE_IN 13
#define CARD 100000
#define HBOT 8
#define KSTEPS 54   // (26*64 + 64) / 32

__global__ __launch_bounds__(256, 1) void dlrm_fused(
    const float* __restrict__ dense_x,
    const int* __restrict__ sparse_x,
    const float* __restrict__ tables,
    const float* __restrict__ w1, const float* __restrict__ b1,
    const float* __restrict__ w2, const float* __restrict__ b2,
    const float* __restrict__ tw1, const float* __restrict__ tb1,
    const float* __restrict__ tw2, const float* __restrict__ tb2,
    float* __restrict__ out)
{
    // B fragments (tw1 as bf16), lane-order layout: conflict-free ds_read_b128
    __shared__ __align__(16) bf16_t Blds[KSTEPS * 64 * 8];   // 55296 B
    // dense-out A fragments: (tile 0..3) x (kstep 0..1) x (lane 0..63) x 8 bf16
    __shared__ __align__(16) bf16_t Dlds[4 * 2 * 64 * 8];    // 8192 B
    __shared__ int idx_lds[64 * NFEAT];                      // 6656 B

    const int tid   = threadIdx.x;
    const int block = blockIdx.x;
    const int lane  = tid & 63;
    const int wave  = tid >> 6;

    // ---- stage sparse indices for this block's 64 samples ----
    const int* sp = sparse_x + (long)block * 64 * NFEAT;
    for (int i = tid; i < 64 * NFEAT; i += 256) idx_lds[i] = sp[i];

    // ---- stage tw1 -> bf16 B-fragments (lane-order) ----
    for (int slot = tid; slot < KSTEPS * 64; slot += 256) {
        int t  = slot >> 6;
        int l  = slot & 63;
        int n  = l & 15;
        int k0 = t * 32 + (l >> 4) * 8;
        bf16x8 v;
        #pragma unroll
        for (int j = 0; j < 8; ++j)
            v[j] = (bf16_t)tw1[(k0 + j) * 16 + n];
        *(bf16x8*)(&Blds[slot * 8]) = v;
    }

    // ---- bottom MLP -> bf16 A-fragments for the dense K-steps ----
    for (int slot = tid; slot < 512; slot += 256) {
        int tile = slot >> 7;
        int tp   = (slot >> 6) & 1;
        int l    = slot & 63;
        int m    = l & 15;
        int q    = l >> 4;
        int s    = block * 64 + tile * 16 + m;
        int d0   = tp * 32 + q * 8;
        float x[DENSE_IN];
        #pragma unroll
        for (int i = 0; i < DENSE_IN; ++i) x[i] = dense_x[s * DENSE_IN + i];
        float h8[HBOT];
        #pragma unroll
        for (int j = 0; j < HBOT; ++j) {
            float acc = b1[j];
            #pragma unroll
            for (int i = 0; i < DENSE_IN; ++i) acc = fmaf(x[i], w1[i * HBOT + j], acc);
            h8[j] = fmaxf(acc, 0.f);
        }
        bf16x8 v;
        #pragma unroll
        for (int jj = 0; jj < 8; ++jj) {
            float acc = b2[d0 + jj];
            #pragma unroll
            for (int j = 0; j < HBOT; ++j) acc = fmaf(h8[j], w2[j * DIM + d0 + jj], acc);
            v[jj] = (bf16_t)acc;
        }
        *(bf16x8*)(&Dlds[slot * 8]) = v;
    }

    __syncthreads();

    // ---- main loop: each wave owns one 16-sample tile ----
    const int tile = wave;
    const int m    = lane & 15;
    const int q    = lane >> 4;
    floatx4 acc = {0.f, 0.f, 0.f, 0.f};

    const int* myidx = &idx_lds[(tile * 16 + m) * NFEAT];

    #pragma unroll 2
    for (int f = 0; f < NFEAT; ++f) {
        int idx = myidx[f];
        const float* row = tables + (long)(f * CARD + idx) * DIM;
        #pragma unroll
        for (int h = 0; h < 2; ++h) {
            const float4 p0 = *(const float4*)(row + h * 32 + q * 8);
            const float4 p1 = *(const float4*)(row + h * 32 + q * 8 + 4);
            bf16x8 a;
            a[0] = (bf16_t)p0.x; a[1] = (bf16_t)p0.y;
            a[2] = (bf16_t)p0.z; a[3] = (bf16_t)p0.w;
            a[4] = (bf16_t)p1.x; a[5] = (bf16_t)p1.y;
            a[6] = (bf16_t)p1.z; a[7] = (bf16_t)p1.w;
            bf16x8 b = *(bf16x8*)(&Blds[((f * 2 + h) * 64 + lane) * 8]);
            acc = __builtin_amdgcn_mfma_f32_16x16x32_bf16(a, b, acc, 0, 0, 0);
        }
    }
    // dense K-steps (t = 52, 53)
    #pragma unroll
    for (int tp = 0; tp < 2; ++tp) {
        bf16x8 a = *(bf16x8*)(&Dlds[((tile * 2 + tp) * 64 + lane) * 8]);
        bf16x8 b = *(bf16x8*)(&Blds[((52 + tp) * 64 + lane) * 8]);
        acc = __builtin_amdgcn_mfma_f32_16x16x32_bf16(a, b, acc, 0, 0, 0);
    }

    // ---- epilogue: bias, relu, x tw2, reduce over 16 hidden, sigmoid ----
    const int h = lane & 15;
    const float bias = tb1[h];
    const float wout = tw2[h];
    float p[4];
    #pragma unroll
    for (int i = 0; i < 4; ++i) p[i] = fmaxf(acc[i] + bias, 0.f) * wout;
    #pragma unroll
    for (int off = 1; off < 16; off <<= 1) {
        #pragma unroll
        for (int i = 0; i < 4; ++i) p[i] += __shfl_xor(p[i], off, 64);
    }
    if (h == 0) {
        const float bout = tb2[0];
        #pragma unroll
        for (int i = 0; i < 4; ++i) {
            float logit = p[i] + bout;
            out[block * 64 + tile * 16 + q * 4 + i] = 1.f / (1.f + expf(-logit));
        }
    }
}

extern "C" void kernel_launch(void* const* d_in, const int* in_sizes, int n_in,
                              void* d_out, int out_size, void* d_ws, size_t ws_size,
                              hipStream_t stream) {
    const float* dense_x = (const float*)d_in[0];
    const int*   sparse_x = (const int*)d_in[1];
    const float* tables  = (const float*)d_in[2];
    const float* w1  = (const float*)d_in[3];
    const float* b1  = (const float*)d_in[4];
    const float* w2  = (const float*)d_in[5];
    const float* b2  = (const float*)d_in[6];
    const float* tw1 = (const float*)d_in[7];
    const float* tb1 = (const float*)d_in[8];
    const float* tw2 = (const float*)d_in[9];
    const float* tb2 = (const float*)d_in[10];
    float* out = (float*)d_out;

    dlrm_fused<<<256, 256, 0, stream>>>(dense_x, sparse_x, tables,
                                        w1, b1, w2, b2,
                                        tw1, tb1, tw2, tb2, out);
}